// Round 10
// baseline (321.997 us; speedup 1.0000x reference)
//
#include <hip/hip_runtime.h>
#include <hip/hip_cooperative_groups.h>

namespace cg = cooperative_groups;

#define B_ 32
#define N_ 4096
#define M_ 32
#define F_ 256
#define A_ 8

typedef float f32x4 __attribute__((ext_vector_type(4)));
typedef int   i32x4 __attribute__((ext_vector_type(4)));

// workspace layout (floats):
//   [0, B*A*F)        anchor_feat (B,A,F)
//   [WS_E2, +B*A)     e2 = anchor_feat @ (a1-a2)
#define WS_AF 0
#define WS_E2 (B_ * A_ * F_)

#define NBLK (B_ * (N_ / 64))  // 2048 blocks x 64 threads; 8 waves/CU -> co-resident

// e1 = h@(a1+a2) is provably irrelevant: e[b,n,k] = e1[b,n] + e2[b,k] and
// softmax over k is invariant to the per-row constant e1 (masked entries are
// -1e9 absolute; exp underflows to 0 either way; all-masked -> uniform 1/8).
// So fatoms is only read for the A=8 anchor rows per batch (stage 1).
__global__ __launch_bounds__(64) void fused_all(const float* __restrict__ fatoms,
                                                const int* __restrict__ agraph,
                                                const int* __restrict__ anchor_idx,
                                                const float* __restrict__ W,
                                                const float* __restrict__ a,
                                                float* __restrict__ ws,
                                                float* __restrict__ out) {
    int lane = threadIdx.x;

    // ---- stage 1: anchor_feat + e2 (blocks 0..255; one bk each) ----
    if (blockIdx.x < B_ * A_) {
        int bk = blockIdx.x;  // b*A_ + k
        int b  = bk >> 3;
        __shared__ float xs[F_];
        int idx = anchor_idx[bk];
        *(f32x4*)(xs + lane * 4) =
            *(const f32x4*)(fatoms + ((size_t)b * N_ + idx) * F_ + lane * 4);
        __syncthreads();
        // thread t owns output features [4t, 4t+4); W rows read as f32x4 (coalesced)
        f32x4 acc0 = {0.f, 0.f, 0.f, 0.f}, acc1 = {0.f, 0.f, 0.f, 0.f};
        const float* wp = W + lane * 4;
        for (int i = 0; i < F_; i += 4) {
            acc0 += xs[i + 0] * *(const f32x4*)(wp + (size_t)(i + 0) * F_);
            acc1 += xs[i + 1] * *(const f32x4*)(wp + (size_t)(i + 1) * F_);
            acc0 += xs[i + 2] * *(const f32x4*)(wp + (size_t)(i + 2) * F_);
            acc1 += xs[i + 3] * *(const f32x4*)(wp + (size_t)(i + 3) * F_);
        }
        f32x4 acc = acc0 + acc1;
        *(f32x4*)(ws + WS_AF + bk * F_ + lane * 4) = acc;
        // e2[bk] = anchor_feat[bk] . (a1 - a2)
        f32x4 da = *(const f32x4*)(a + lane * 4);
        f32x4 db = *(const f32x4*)(a + F_ + lane * 4);
        f32x4 dd = da - db;
        float part = acc.x * dd.x + acc.y * dd.y + acc.z * dd.z + acc.w * dd.w;
#pragma unroll
        for (int off = 32; off > 0; off >>= 1) part += __shfl_xor(part, off);
        if (lane == 0) ws[WS_E2 + bk] = part;
    }
    __threadfence();           // make ws writes device-visible
    cg::this_grid().sync();    // one bubble-free "launch boundary"

    // ---- stage 2: main (all 2048 blocks; 64 rows each) ----
    int b    = blockIdx.x >> 6;
    int row0 = (blockIdx.x & 63) * 64;

    // critical-path agraph loads first (row = row0 + lane)
    const i32x4* gp = (const i32x4*)(agraph + ((size_t)b * N_ + row0 + lane) * M_);
    i32x4 g[M_ / 4];
#pragma unroll
    for (int j = 0; j < M_ / 4; ++j) g[j] = gp[j];

    const float* af = ws + WS_AF + b * (A_ * F_);
    __shared__ float attn_s[64][A_];

    int   anch[A_];
    float e2r[A_];
#pragma unroll
    for (int k = 0; k < A_; ++k) {
        anch[k] = anchor_idx[b * A_ + k];
        e2r[k]  = ws[WS_E2 + b * A_ + k];
    }
    float m8 = e2r[0];
#pragma unroll
    for (int k = 1; k < A_; ++k) m8 = fmaxf(m8, e2r[k]);
    float E[A_];
#pragma unroll
    for (int k = 0; k < A_; ++k) E[k] = __expf(e2r[k] - m8);

    f32x4 afr[A_];
#pragma unroll
    for (int k = 0; k < A_; ++k) afr[k] = *(const f32x4*)(af + k * F_ + lane * 4);

    {
        unsigned mk = 0;
#pragma unroll
        for (int j = 0; j < M_ / 4; ++j) {
#pragma unroll
            for (int k = 0; k < A_; ++k) {
                int hit = (g[j].x == anch[k]) | (g[j].y == anch[k]) |
                          (g[j].z == anch[k]) | (g[j].w == anch[k]);
                mk |= hit ? (1u << k) : 0u;
            }
        }
        float p[A_], s = 0.f;
#pragma unroll
        for (int k = 0; k < A_; ++k) { p[k] = (mk & (1u << k)) ? E[k] : 0.f; s += p[k]; }
        if (mk == 0) {  // all masked -> uniform
#pragma unroll
            for (int k = 0; k < A_; ++k) p[k] = 1.f;
            s = 8.f;
        }
        float rinv = __builtin_amdgcn_rcpf(s);
#pragma unroll
        for (int k = 0; k < A_; ++k) attn_s[lane][k] = p[k] * rinv;
    }
    __syncthreads();

    size_t base = ((size_t)b * N_ + row0) * F_ + lane * 4;
    for (int r0 = 0; r0 < 64; r0 += 4) {
        f32x4 o[4];
#pragma unroll
        for (int u = 0; u < 4; ++u) {
            f32x4 pa = *(const f32x4*)&attn_s[r0 + u][0];  // broadcast reads
            f32x4 pb = *(const f32x4*)&attn_s[r0 + u][4];
            f32x4 t = pa.x * afr[0];
            t += pa.y * afr[1];
            t += pa.z * afr[2];
            t += pa.w * afr[3];
            t += pb.x * afr[4];
            t += pb.y * afr[5];
            t += pb.z * afr[6];
            t += pb.w * afr[7];
            o[u] = t;
        }
#pragma unroll
        for (int u = 0; u < 4; ++u)
            *(f32x4*)(out + base + (size_t)(r0 + u) * F_) = o[u];
    }
}

extern "C" void kernel_launch(void* const* d_in, const int* in_sizes, int n_in,
                              void* d_out, int out_size, void* d_ws, size_t ws_size,
                              hipStream_t stream) {
    const float* fatoms     = (const float*)d_in[0];
    const int*   agraph     = (const int*)d_in[1];
    const int*   anchor_idx = (const int*)d_in[2];
    const float* W          = (const float*)d_in[3];
    const float* a          = (const float*)d_in[4];
    float*       out        = (float*)d_out;
    float*       ws         = (float*)d_ws;

    void* args[] = {(void*)&fatoms, (void*)&agraph, (void*)&anchor_idx,
                    (void*)&W, (void*)&a, (void*)&ws, (void*)&out};
    hipLaunchCooperativeKernel(reinterpret_cast<const void*>(fused_all),
                               dim3(NBLK), dim3(64), args, 0, stream);
}